// Round 5
// baseline (387.787 us; speedup 1.0000x reference)
//
#include <hip/hip_runtime.h>
#include <hip/hip_bf16.h>

typedef unsigned short u16;
typedef unsigned int u32;
typedef short short8 __attribute__((ext_vector_type(8)));
typedef float f32x4 __attribute__((ext_vector_type(4)));

#define OUTD 7
#define NROI 1024
#define CH 256
#define KDIM 12544   // 256*49
#define NHID 1024
#define KSPLIT 14    // 12544 = 14 * 896 = 14 * (14*64)

__device__ __forceinline__ float bf_lo(u32 u) {
    union { u32 i; float f; } v; v.i = u << 16; return v.f;
}
__device__ __forceinline__ float bf_hi(u32 u) {
    union { u32 i; float f; } v; v.i = u & 0xffff0000u; return v.f;
}
__device__ __forceinline__ u16 f2b(float f) {
    return (u16)(__bfloat16_as_ushort(__float2bfloat16(f)));
}
__device__ __forceinline__ void async16(const void* g, void* l) {
    __builtin_amdgcn_global_load_lds((const __attribute__((address_space(1))) u32*)g,
                                     (__attribute__((address_space(3))) u32*)l, 16, 0, 0);
}

// ---------------- fused prep: feat transpose + w1 transpose + w2 transpose ----------------
// Plain vector loads (NOT global_load_lds: the per-CU LDS-DMA engine holds only ~4
// outstanding requests -> 4KB/900cyc = 2.3TB/s cap at HBM latency, the measured wall).
// 16 float4 loads burst into named regs; asm memory fence stops the compiler sinking
// them (r2 failure mode: VGPR=44 proved the burst was refused). fp32 LDS tile with
// XOR-on-px-quad swizzle: b128 stores free, read-back b32 2-way (free).
// blocks [0,2048): features (B,C,H,W) fp32 -> featT (B,H,W,C) bf16  (128px x 128ch)
// blocks [2048,2832): w1 (K,N) fp32 -> w1t (N,K) bf16               (128k x 128n)
// blocks [2832,2881): w2 (K,49) fp32 -> w2t (49,K) fp32
__global__ __launch_bounds__(256) void prep(const float* __restrict__ f,
                                            const float* __restrict__ w1,
                                            const float* __restrict__ w2,
                                            u16* __restrict__ ft,
                                            u16* __restrict__ w1t,
                                            float* __restrict__ w2t) {
    __shared__ __align__(16) u32 smem[16384];   // 64 KB
    float* smf = (float*)smem;
    int bid = blockIdx.x;
    int tid = threadIdx.x;
    if (bid < 2048) {
        int pb  = bid & 511;         // px block (128 px each)
        int cbk = (bid >> 9) & 1;    // channel block (128 ch each)
        int b   = bid >> 10;
        const float* src = f + ((size_t)(b * CH + cbk * 128)) * 65536 + (size_t)pb * 128;
        // burst: 16 independent float4 loads (16KB in flight per wave)
        float4 v[16];
#pragma unroll
        for (int it = 0; it < 16; ++it) {
            int id = tid + 256 * it;          // 0..4095
            int c = id >> 5, px4 = id & 31;   // c 0..127, px-quad 0..31 (512B/row)
            v[it] = *(const float4*)(src + (size_t)c * 65536 + px4 * 4);
        }
        asm volatile("" ::: "memory");        // loads may not sink below this fence
        // LDS [c][px] fp32, slot-swizzled: word = c*128 + (px4 ^ ((c>>3)&7))*4 + j
#pragma unroll
        for (int it = 0; it < 16; ++it) {
            int id = tid + 256 * it;
            int c = id >> 5, px4 = id & 31;
            int slot = px4 ^ ((c >> 3) & 7);
            *(float4*)&smem[c * 128 + slot * 4] = v[it];
        }
        __syncthreads();
        // read-back: thread = (chg = ch-octet 0..15, px). 8x ds_read_b32 down the
        // c-column (2-way bank alias only), cvt+pack, one uint4 store (256B/16 lanes).
        int chg = tid & 15;
        int s = chg & 7;
        u16* dst = ft + ((size_t)b * 65536 + (size_t)pb * 128) * CH + cbk * 128 + chg * 8;
#pragma unroll
        for (int it = 0; it < 8; ++it) {
            int px = (tid >> 4) + 16 * it;    // 0..127
            int base = ((px >> 2) ^ s) * 4 + (px & 3);
            u32 o[4];
#pragma unroll
            for (int j2 = 0; j2 < 4; ++j2) {
                float x0 = smf[(8 * chg + 2 * j2 + 0) * 128 + base];
                float x1 = smf[(8 * chg + 2 * j2 + 1) * 128 + base];
                o[j2] = (u32)f2b(x0) | ((u32)f2b(x1) << 16);
            }
            *(uint4*)(dst + (size_t)px * CH) = *(uint4*)o;
        }
    } else if (bid < 2832) {
        int t = bid - 2048;                  // 0..783
        int kb = t % 98, nb = t / 98;        // 128 k-rows x 128 n-cols
        const float* src = w1 + (size_t)(kb * 128) * NHID + nb * 128;
        float4 v[16];
#pragma unroll
        for (int it = 0; it < 16; ++it) {
            int id = tid + 256 * it;
            int k = id >> 5, n4 = id & 31;
            v[it] = *(const float4*)(src + (size_t)k * NHID + n4 * 4);
        }
        asm volatile("" ::: "memory");
#pragma unroll
        for (int it = 0; it < 16; ++it) {
            int id = tid + 256 * it;
            int k = id >> 5, n4 = id & 31;
            int slot = n4 ^ ((k >> 3) & 7);
            *(float4*)&smem[k * 128 + slot * 4] = v[it];
        }
        __syncthreads();
        int kg = tid & 15;
        int s = kg & 7;
        u16* dstw = w1t + (size_t)(nb * 128) * KDIM + kb * 128 + kg * 8;
#pragma unroll
        for (int it = 0; it < 8; ++it) {
            int n = (tid >> 4) + 16 * it;    // 0..127
            int base = ((n >> 2) ^ s) * 4 + (n & 3);
            u32 o[4];
#pragma unroll
            for (int j2 = 0; j2 < 4; ++j2) {
                float x0 = smf[(8 * kg + 2 * j2 + 0) * 128 + base];
                float x1 = smf[(8 * kg + 2 * j2 + 1) * 128 + base];
                o[j2] = (u32)f2b(x0) | ((u32)f2b(x1) << 16);
            }
            *(uint4*)(dstw + (size_t)n * KDIM) = *(uint4*)o;
        }
    } else {
        int j = bid - 2832;                  // 0..48
        for (int k = tid; k < NHID; k += 256)
            w2t[(size_t)j * NHID + k] = w2[(size_t)k * 49 + j];
    }
}

// ---------------- rotated RoI align: featT -> flat (bf16) ----------------
__global__ __launch_bounds__(256) void roi_align(const u16* __restrict__ ft,
                                                 const float* __restrict__ rois,
                                                 u16* __restrict__ flat) {
    __shared__ u16 sbuf[49 * 260];   // [bin][c], pad 260 keeps uint2 alignment; 25480 B
    int i = blockIdx.x;
    int tid = threadIdx.x;
    int lane = tid & 63, w = tid >> 6;
    float r0 = rois[i * 6 + 0], r1 = rois[i * 6 + 1], r2 = rois[i * 6 + 2];
    float r3 = rois[i * 6 + 3], r4 = rois[i * 6 + 4], th = rois[i * 6 + 5];
    int b = (int)r0;
    float cx = r1 * 0.125f, cy = r2 * 0.125f;
    float rw = fmaxf(r3 * 0.125f, 1.0f), rh = fmaxf(r4 * 0.125f, 1.0f);
    float bw = rw * (1.0f / 7.0f), bh = rh * (1.0f / 7.0f);
    float ct = cosf(th), st = sinf(th);
    const u16* fb = ft + (size_t)b * 65536 * CH;
    int coff = lane * 4;

    int start = w * 12 + (w > 0 ? 1 : 0);
    int cnt = (w == 0) ? 13 : 12;
    for (int bi = 0; bi < cnt; ++bi) {
        int bin = start + bi;
        int ph = bin / 7, pw = bin - ph * 7;
        float a0 = 0.f, a1 = 0.f, a2 = 0.f, a3 = 0.f;
#pragma unroll
        for (int s = 0; s < 4; ++s) {
            int sy = s >> 1, sx2 = s & 1;
            float yy = -rh * 0.5f + ((float)ph + ((float)sy + 0.5f) * 0.5f) * bh;
            float xx = -rw * 0.5f + ((float)pw + ((float)sx2 + 0.5f) * 0.5f) * bw;
            float xs = xx * ct - yy * st + cx;
            float ys = xx * st + yy * ct + cy;
            bool valid = (ys > -1.0f) && (ys < 256.0f) && (xs > -1.0f) && (xs < 256.0f);
            float ysc = fminf(fmaxf(ys, 0.f), 255.f);
            float xsc = fminf(fmaxf(xs, 0.f), 255.f);
            int yl = (int)floorf(ysc), xl = (int)floorf(xsc);
            int yh = min(yl + 1, 255), xh = min(xl + 1, 255);
            float ly = ysc - (float)yl, lx = xsc - (float)xl;
            float hy = 1.f - ly, hx = 1.f - lx;
            float w11 = hy * hx, w12 = hy * lx, w21 = ly * hx, w22 = ly * lx;
            if (!valid) { w11 = w12 = w21 = w22 = 0.f; }
            uint2 v11 = *(const uint2*)(fb + (((size_t)yl * 256 + xl) << 8) + coff);
            uint2 v12 = *(const uint2*)(fb + (((size_t)yl * 256 + xh) << 8) + coff);
            uint2 v21 = *(const uint2*)(fb + (((size_t)yh * 256 + xl) << 8) + coff);
            uint2 v22 = *(const uint2*)(fb + (((size_t)yh * 256 + xh) << 8) + coff);
            a0 += w11 * bf_lo(v11.x) + w12 * bf_lo(v12.x) + w21 * bf_lo(v21.x) + w22 * bf_lo(v22.x);
            a1 += w11 * bf_hi(v11.x) + w12 * bf_hi(v12.x) + w21 * bf_hi(v21.x) + w22 * bf_hi(v22.x);
            a2 += w11 * bf_lo(v11.y) + w12 * bf_lo(v12.y) + w21 * bf_lo(v21.y) + w22 * bf_lo(v22.y);
            a3 += w11 * bf_hi(v11.y) + w12 * bf_hi(v12.y) + w21 * bf_hi(v21.y) + w22 * bf_hi(v22.y);
        }
        uint2 o;
        o.x = (u32)f2b(a0 * 0.25f) | ((u32)f2b(a1 * 0.25f) << 16);
        o.y = (u32)f2b(a2 * 0.25f) | ((u32)f2b(a3 * 0.25f) << 16);
        *(uint2*)(sbuf + bin * 260 + coff) = o;
    }
    __syncthreads();
    // write flat[i][c*49+bin], 4 elems/thread/iter, coalesced uint2 stores
    uint2* fl = (uint2*)(flat + (size_t)i * KDIM);
#pragma unroll 1
    for (int k = tid; k < 3136; k += 256) {
        int e = k * 4;
        int c = e / 49, bn = e - c * 49;
        u16 r0_ = sbuf[bn * 260 + c]; if (++bn == 49) { bn = 0; ++c; }
        u16 r1_ = sbuf[bn * 260 + c]; if (++bn == 49) { bn = 0; ++c; }
        u16 r2_ = sbuf[bn * 260 + c]; if (++bn == 49) { bn = 0; ++c; }
        u16 r3_ = sbuf[bn * 260 + c];
        uint2 o;
        o.x = (u32)r0_ | ((u32)r1_ << 16);
        o.y = (u32)r2_ | ((u32)r3_ << 16);
        fl[k] = o;
    }
}

// ---------------- GEMM1: flat[1024,12544]bf16 @ w1t[1024,12544]^T -> part fp32 ----------------
// 256x256 tile, 8 waves (2Mx4N), BK=64, KSPLIT=14 (K-run = 14*64 = 896 exactly).
// 2-phase double-buffer: prefetch slice s+1 via global_load_lds during MFMA on s
// (sources are L2/L3-resident, where the LDS-DMA engine's ~4-deep queue still feeds);
// counted s_waitcnt vmcnt(8) keeps the prefetch in flight across the barrier.
// XOR-8 swizzle applied on the GLOBAL side (global_load_lds dest must be linear).
__global__ __launch_bounds__(512) void gemm1(const u16* __restrict__ A,
                                             const u16* __restrict__ Bt,
                                             float* __restrict__ part) {
    const int K = KDIM;
    int nb = blockIdx.x, mb = blockIdx.y, ks = blockIdx.z;
    const int steps = 14;
    int kbase = ks * 896;
    __shared__ __align__(16) u16 As[2][256 * 64];   // 64KB
    __shared__ __align__(16) u16 Bs[2][256 * 64];   // 64KB
    int tid = threadIdx.x;
    int lane = tid & 63, w = tid >> 6;   // w 0..7
    int wm = w >> 2, wn = w & 3;         // wave grid 2M x 4N; wave tile 128x64
    f32x4 acc[8][4] = {};
    const u16* Ab = A + (size_t)(mb * 256) * K;
    const u16* Bb = Bt + (size_t)(nb * 256) * K;

    auto stage = [&](int buf, int kk) {
#pragma unroll
        for (int j = 0; j < 4; ++j) {
            int c = w * 4 + j;                 // 0..31
            int cid = c * 64 + lane;           // 0..2047
            int row = cid >> 3, pq = cid & 7;  // row 0..255
            int q = pq ^ (row & 7);            // global-side swizzle
            async16(Ab + (size_t)row * K + kk + q * 8, &As[buf][c * 512 + lane * 8]);
            async16(Bb + (size_t)row * K + kk + q * 8, &Bs[buf][c * 512 + lane * 8]);
        }
    };

    stage(0, kbase);
    int cur = 0;
    for (int s = 0; s < steps; ++s) {
        if (s + 1 < steps) {
            stage(cur ^ 1, kbase + (s + 1) * 64);            // 8 new loads in flight
            asm volatile("s_waitcnt vmcnt(8)" ::: "memory"); // own cur-buffer loads done
        } else {
            asm volatile("s_waitcnt vmcnt(0)" ::: "memory");
        }
        __builtin_amdgcn_s_barrier();                        // all waves' cur-buffer done
        const u16* Asb = &As[cur][0];
        const u16* Bsb = &Bs[cur][0];
#pragma unroll
        for (int kh = 0; kh < 2; ++kh) {
            short8 af[8], bf[4];
            int q = kh * 4 + (lane >> 4);
#pragma unroll
            for (int t = 0; t < 8; ++t) {
                int r = wm * 128 + t * 16 + (lane & 15);
                int pq = q ^ (r & 7);
                af[t] = *(const short8*)(Asb + r * 64 + pq * 8);
            }
#pragma unroll
            for (int t = 0; t < 4; ++t) {
                int rb = wn * 64 + t * 16 + (lane & 15);
                int pqb = q ^ (rb & 7);
                bf[t] = *(const short8*)(Bsb + rb * 64 + pqb * 8);
            }
#pragma unroll
            for (int mt = 0; mt < 8; ++mt)
#pragma unroll
                for (int nt = 0; nt < 4; ++nt)
                    acc[mt][nt] = __builtin_amdgcn_mfma_f32_16x16x32_bf16(af[mt], bf[nt], acc[mt][nt], 0, 0, 0);
        }
        __builtin_amdgcn_s_barrier();                        // reads of cur done before overwrite
        cur ^= 1;
    }
    float* P = part + (size_t)ks * NROI * NHID;
    int m_base = mb * 256 + wm * 128, n_base = nb * 256 + wn * 64;
#pragma unroll
    for (int mt = 0; mt < 8; ++mt)
#pragma unroll
        for (int nt = 0; nt < 4; ++nt)
#pragma unroll
            for (int i = 0; i < 4; ++i) {
                int m = m_base + mt * 16 + (lane >> 4) * 4 + i;
                int n = n_base + nt * 16 + (lane & 15);
                P[(size_t)m * NHID + n] = acc[mt][nt][i];
            }
}

// ---------------- fused: split-K reduce + bias + relu + GEMM2 + sigmoid + apply ----------------
__global__ __launch_bounds__(256) void gemm2_apply(const float* __restrict__ part,
                                                   const float* __restrict__ b1,
                                                   const float* __restrict__ w2t,
                                                   const float* __restrict__ b2,
                                                   const u16* __restrict__ flat,
                                                   float* __restrict__ out) {
    __shared__ __align__(16) float hrow[NHID];
    __shared__ float partial[256];
    __shared__ float mrow[49];
    int i = blockIdx.x;
    int tid = threadIdx.x;
    // reduce split-K partials for this roi's hid row + bias + relu, into LDS
    {
        float4 s = ((const float4*)b1)[tid];
        size_t base = (size_t)i * 256 + tid;   // float4 index within one K-slice
#pragma unroll
        for (int j = 0; j < KSPLIT; ++j) {
            float4 p = ((const float4*)part)[(size_t)j * 262144 + base];
            s.x += p.x; s.y += p.y; s.z += p.z; s.w += p.w;
        }
        float4 r;
        r.x = fmaxf(s.x, 0.f); r.y = fmaxf(s.y, 0.f);
        r.z = fmaxf(s.z, 0.f); r.w = fmaxf(s.w, 0.f);
        ((float4*)hrow)[tid] = r;
    }
    __syncthreads();
    float p = 0.f;
    if (tid < 245) {
        int j = tid / 5, kc = tid - (tid / 5) * 5;
        int k0 = (256 * kc) / 5, k1 = (256 * (kc + 1)) / 5;   // float4 chunks
        const float4* wv = (const float4*)(w2t + (size_t)j * NHID);
        const float4* hv = (const float4*)hrow;
        for (int k = k0; k < k1; ++k) {
            float4 a = hv[k], b = wv[k];
            p += a.x * b.x + a.y * b.y + a.z * b.z + a.w * b.w;
        }
    }
    partial[tid] = p;
    __syncthreads();
    if (tid < 49) {
        float s = b2[tid];
#pragma unroll
        for (int q = 0; q < 5; ++q) s += partial[tid * 5 + q];
        mrow[tid] = 1.f / (1.f + expf(-s));
    }
    __syncthreads();
    const uint2* fl = (const uint2*)(flat + (size_t)i * KDIM);
    float4* op = (float4*)(out + (size_t)i * KDIM);
#pragma unroll 1
    for (int idx = tid; idx < 3136; idx += 256) {
        uint2 v = fl[idx];
        int e = idx * 4;
        int pp = e - (e / 49) * 49;
        float4 r;
        r.x = bf_lo(v.x) * mrow[pp]; if (++pp == 49) pp = 0;
        r.y = bf_hi(v.x) * mrow[pp]; if (++pp == 49) pp = 0;
        r.z = bf_lo(v.y) * mrow[pp]; if (++pp == 49) pp = 0;
        r.w = bf_hi(v.y) * mrow[pp];
        op[idx] = r;
    }
}

extern "C" void kernel_launch(void* const* d_in, const int* in_sizes, int n_in,
                              void* d_out, int out_size, void* d_ws, size_t ws_size,
                              hipStream_t stream) {
    const float* features = (const float*)d_in[0];
    const float* rois     = (const float*)d_in[1];
    const float* w1       = (const float*)d_in[2];
    const float* b1       = (const float*)d_in[3];
    const float* w2       = (const float*)d_in[4];
    const float* b2       = (const float*)d_in[5];
    float* out = (float*)d_out;
    char* ws = (char*)d_ws;

    u16* featT  = (u16*)(ws);                      // 67,108,864
    u16* flat   = (u16*)(ws + 67108864);           // 25,690,112
    u16* w1t    = (u16*)(ws + 92798976);           // 25,690,112
    float* part = (float*)(ws + 118489088);        // 58,720,256 (KSPLIT=14)
    float* w2t  = (float*)(ws + 177209344);        // 200,704

    prep<<<2881, 256, 0, stream>>>(features, w1, w2, featT, w1t, w2t);
    roi_align<<<NROI, 256, 0, stream>>>(featT, rois, flat);
    gemm1<<<dim3(4, 4, KSPLIT), 512, 0, stream>>>(flat, w1t, part);
    gemm2_apply<<<NROI, 256, 0, stream>>>(part, b1, w2t, b2, flat, out);
}

// Round 6
// 383.842 us; speedup vs baseline: 1.0103x; 1.0103x over previous
//
#include <hip/hip_runtime.h>
#include <hip/hip_bf16.h>

typedef unsigned short u16;
typedef unsigned int u32;
typedef short short8 __attribute__((ext_vector_type(8)));
typedef float f32x4 __attribute__((ext_vector_type(4)));

#define OUTD 7
#define NROI 1024
#define CH 256
#define KDIM 12544   // 256*49
#define NHID 1024
#define KSPLIT 14    // 12544 = 14 * 896 = 14 * (14*64)
#define G2 4         // rois per gemm2 block

__device__ __forceinline__ float bf_lo(u32 u) {
    union { u32 i; float f; } v; v.i = u << 16; return v.f;
}
__device__ __forceinline__ float bf_hi(u32 u) {
    union { u32 i; float f; } v; v.i = u & 0xffff0000u; return v.f;
}
__device__ __forceinline__ u16 f2b(float f) {
    return (u16)(__bfloat16_as_ushort(__float2bfloat16(f)));
}
__device__ __forceinline__ void async16(const void* g, void* l) {
    __builtin_amdgcn_global_load_lds((const __attribute__((address_space(1))) u32*)g,
                                     (__attribute__((address_space(3))) u32*)l, 16, 0, 0);
}

// ---------------- features (B,C,H,W) fp32 -> featT (B,H,W,C) bf16 ----------------
// (body identical to round-5 prep feat branch; split out for per-kernel attribution)
__global__ __launch_bounds__(256) void tfeat(const float* __restrict__ f,
                                             u16* __restrict__ ft) {
    __shared__ __align__(16) u32 smem[16384];   // 64 KB
    float* smf = (float*)smem;
    int bid = blockIdx.x;
    int tid = threadIdx.x;
    int pb  = bid & 511;         // px block (128 px each)
    int cbk = (bid >> 9) & 1;    // channel block (128 ch each)
    int b   = bid >> 10;
    const float* src = f + ((size_t)(b * CH + cbk * 128)) * 65536 + (size_t)pb * 128;
    float4 v[16];
#pragma unroll
    for (int it = 0; it < 16; ++it) {
        int id = tid + 256 * it;          // 0..4095
        int c = id >> 5, px4 = id & 31;   // c 0..127, px-quad 0..31
        v[it] = *(const float4*)(src + (size_t)c * 65536 + px4 * 4);
    }
    asm volatile("" ::: "memory");        // loads may not sink below this fence
#pragma unroll
    for (int it = 0; it < 16; ++it) {
        int id = tid + 256 * it;
        int c = id >> 5, px4 = id & 31;
        int slot = px4 ^ ((c >> 3) & 7);
        *(float4*)&smem[c * 128 + slot * 4] = v[it];
    }
    __syncthreads();
    int chg = tid & 15;
    int s = chg & 7;
    u16* dst = ft + ((size_t)b * 65536 + (size_t)pb * 128) * CH + cbk * 128 + chg * 8;
#pragma unroll
    for (int it = 0; it < 8; ++it) {
        int px = (tid >> 4) + 16 * it;    // 0..127
        int base = ((px >> 2) ^ s) * 4 + (px & 3);
        u32 o[4];
#pragma unroll
        for (int j2 = 0; j2 < 4; ++j2) {
            float x0 = smf[(8 * chg + 2 * j2 + 0) * 128 + base];
            float x1 = smf[(8 * chg + 2 * j2 + 1) * 128 + base];
            o[j2] = (u32)f2b(x0) | ((u32)f2b(x1) << 16);
        }
        *(uint4*)(dst + (size_t)px * CH) = *(uint4*)o;
    }
}

// ---------------- w1 (K,N) fp32 -> w1t (N,K) bf16 ----------------
__global__ __launch_bounds__(256) void tw1(const float* __restrict__ w1,
                                           u16* __restrict__ w1t) {
    __shared__ __align__(16) u32 smem[16384];
    float* smf = (float*)smem;
    int t = blockIdx.x;                  // 0..783
    int tid = threadIdx.x;
    int kb = t % 98, nb = t / 98;        // 128 k-rows x 128 n-cols
    const float* src = w1 + (size_t)(kb * 128) * NHID + nb * 128;
    float4 v[16];
#pragma unroll
    for (int it = 0; it < 16; ++it) {
        int id = tid + 256 * it;
        int k = id >> 5, n4 = id & 31;
        v[it] = *(const float4*)(src + (size_t)k * NHID + n4 * 4);
    }
    asm volatile("" ::: "memory");
#pragma unroll
    for (int it = 0; it < 16; ++it) {
        int id = tid + 256 * it;
        int k = id >> 5, n4 = id & 31;
        int slot = n4 ^ ((k >> 3) & 7);
        *(float4*)&smem[k * 128 + slot * 4] = v[it];
    }
    __syncthreads();
    int kg = tid & 15;
    int s = kg & 7;
    u16* dstw = w1t + (size_t)(nb * 128) * KDIM + kb * 128 + kg * 8;
#pragma unroll
    for (int it = 0; it < 8; ++it) {
        int n = (tid >> 4) + 16 * it;    // 0..127
        int base = ((n >> 2) ^ s) * 4 + (n & 3);
        u32 o[4];
#pragma unroll
        for (int j2 = 0; j2 < 4; ++j2) {
            float x0 = smf[(8 * kg + 2 * j2 + 0) * 128 + base];
            float x1 = smf[(8 * kg + 2 * j2 + 1) * 128 + base];
            o[j2] = (u32)f2b(x0) | ((u32)f2b(x1) << 16);
        }
        *(uint4*)(dstw + (size_t)n * KDIM) = *(uint4*)o;
    }
}

// ---------------- w2 (K,49) fp32 -> w2t (49,K) ----------------
__global__ __launch_bounds__(256) void tw2(const float* __restrict__ w2,
                                           float* __restrict__ w2t) {
    int j = blockIdx.x;   // 0..48
    for (int k = threadIdx.x; k < NHID; k += 256)
        w2t[(size_t)j * NHID + k] = w2[(size_t)k * 49 + j];
}

// ---------------- rotated RoI align: featT -> flat (bf16) ----------------
__global__ __launch_bounds__(256) void roi_align(const u16* __restrict__ ft,
                                                 const float* __restrict__ rois,
                                                 u16* __restrict__ flat) {
    __shared__ u16 sbuf[49 * 260];   // [bin][c], pad 260 keeps uint2 alignment; 25480 B
    int i = blockIdx.x;
    int tid = threadIdx.x;
    int lane = tid & 63, w = tid >> 6;
    float r0 = rois[i * 6 + 0], r1 = rois[i * 6 + 1], r2 = rois[i * 6 + 2];
    float r3 = rois[i * 6 + 3], r4 = rois[i * 6 + 4], th = rois[i * 6 + 5];
    int b = (int)r0;
    float cx = r1 * 0.125f, cy = r2 * 0.125f;
    float rw = fmaxf(r3 * 0.125f, 1.0f), rh = fmaxf(r4 * 0.125f, 1.0f);
    float bw = rw * (1.0f / 7.0f), bh = rh * (1.0f / 7.0f);
    float ct = cosf(th), st = sinf(th);
    const u16* fb = ft + (size_t)b * 65536 * CH;
    int coff = lane * 4;

    int start = w * 12 + (w > 0 ? 1 : 0);
    int cnt = (w == 0) ? 13 : 12;
    for (int bi = 0; bi < cnt; ++bi) {
        int bin = start + bi;
        int ph = bin / 7, pw = bin - ph * 7;
        float a0 = 0.f, a1 = 0.f, a2 = 0.f, a3 = 0.f;
#pragma unroll
        for (int s = 0; s < 4; ++s) {
            int sy = s >> 1, sx2 = s & 1;
            float yy = -rh * 0.5f + ((float)ph + ((float)sy + 0.5f) * 0.5f) * bh;
            float xx = -rw * 0.5f + ((float)pw + ((float)sx2 + 0.5f) * 0.5f) * bw;
            float xs = xx * ct - yy * st + cx;
            float ys = xx * st + yy * ct + cy;
            bool valid = (ys > -1.0f) && (ys < 256.0f) && (xs > -1.0f) && (xs < 256.0f);
            float ysc = fminf(fmaxf(ys, 0.f), 255.f);
            float xsc = fminf(fmaxf(xs, 0.f), 255.f);
            int yl = (int)floorf(ysc), xl = (int)floorf(xsc);
            int yh = min(yl + 1, 255), xh = min(xl + 1, 255);
            float ly = ysc - (float)yl, lx = xsc - (float)xl;
            float hy = 1.f - ly, hx = 1.f - lx;
            float w11 = hy * hx, w12 = hy * lx, w21 = ly * hx, w22 = ly * lx;
            if (!valid) { w11 = w12 = w21 = w22 = 0.f; }
            uint2 v11 = *(const uint2*)(fb + (((size_t)yl * 256 + xl) << 8) + coff);
            uint2 v12 = *(const uint2*)(fb + (((size_t)yl * 256 + xh) << 8) + coff);
            uint2 v21 = *(const uint2*)(fb + (((size_t)yh * 256 + xl) << 8) + coff);
            uint2 v22 = *(const uint2*)(fb + (((size_t)yh * 256 + xh) << 8) + coff);
            a0 += w11 * bf_lo(v11.x) + w12 * bf_lo(v12.x) + w21 * bf_lo(v21.x) + w22 * bf_lo(v22.x);
            a1 += w11 * bf_hi(v11.x) + w12 * bf_hi(v12.x) + w21 * bf_hi(v21.x) + w22 * bf_hi(v22.x);
            a2 += w11 * bf_lo(v11.y) + w12 * bf_lo(v12.y) + w21 * bf_lo(v21.y) + w22 * bf_lo(v22.y);
            a3 += w11 * bf_hi(v11.y) + w12 * bf_hi(v12.y) + w21 * bf_hi(v21.y) + w22 * bf_hi(v22.y);
        }
        uint2 o;
        o.x = (u32)f2b(a0 * 0.25f) | ((u32)f2b(a1 * 0.25f) << 16);
        o.y = (u32)f2b(a2 * 0.25f) | ((u32)f2b(a3 * 0.25f) << 16);
        *(uint2*)(sbuf + bin * 260 + coff) = o;
    }
    __syncthreads();
    // write flat[i][c*49+bin], 4 elems/thread/iter, coalesced uint2 stores
    uint2* fl = (uint2*)(flat + (size_t)i * KDIM);
#pragma unroll 1
    for (int k = tid; k < 3136; k += 256) {
        int e = k * 4;
        int c = e / 49, bn = e - c * 49;
        u16 r0_ = sbuf[bn * 260 + c]; if (++bn == 49) { bn = 0; ++c; }
        u16 r1_ = sbuf[bn * 260 + c]; if (++bn == 49) { bn = 0; ++c; }
        u16 r2_ = sbuf[bn * 260 + c]; if (++bn == 49) { bn = 0; ++c; }
        u16 r3_ = sbuf[bn * 260 + c];
        uint2 o;
        o.x = (u32)r0_ | ((u32)r1_ << 16);
        o.y = (u32)r2_ | ((u32)r3_ << 16);
        fl[k] = o;
    }
}

// ---------------- GEMM1: flat[1024,12544]bf16 @ w1t[1024,12544]^T -> part fp32 ----------------
// 256x256 tile, 8 waves (2Mx4N), BK=64, KSPLIT=14 (K-run = 14*64 = 896 exactly).
// 2-phase double-buffer with counted s_waitcnt vmcnt(8); XOR-8 swizzle on global side.
__global__ __launch_bounds__(512) void gemm1(const u16* __restrict__ A,
                                             const u16* __restrict__ Bt,
                                             float* __restrict__ part) {
    const int K = KDIM;
    int nb = blockIdx.x, mb = blockIdx.y, ks = blockIdx.z;
    const int steps = 14;
    int kbase = ks * 896;
    __shared__ __align__(16) u16 As[2][256 * 64];   // 64KB
    __shared__ __align__(16) u16 Bs[2][256 * 64];   // 64KB
    int tid = threadIdx.x;
    int lane = tid & 63, w = tid >> 6;   // w 0..7
    int wm = w >> 2, wn = w & 3;         // wave grid 2M x 4N; wave tile 128x64
    f32x4 acc[8][4] = {};
    const u16* Ab = A + (size_t)(mb * 256) * K;
    const u16* Bb = Bt + (size_t)(nb * 256) * K;

    auto stage = [&](int buf, int kk) {
#pragma unroll
        for (int j = 0; j < 4; ++j) {
            int c = w * 4 + j;                 // 0..31
            int cid = c * 64 + lane;           // 0..2047
            int row = cid >> 3, pq = cid & 7;  // row 0..255
            int q = pq ^ (row & 7);            // global-side swizzle
            async16(Ab + (size_t)row * K + kk + q * 8, &As[buf][c * 512 + lane * 8]);
            async16(Bb + (size_t)row * K + kk + q * 8, &Bs[buf][c * 512 + lane * 8]);
        }
    };

    stage(0, kbase);
    int cur = 0;
    for (int s = 0; s < steps; ++s) {
        if (s + 1 < steps) {
            stage(cur ^ 1, kbase + (s + 1) * 64);            // 8 new loads in flight
            asm volatile("s_waitcnt vmcnt(8)" ::: "memory"); // own cur-buffer loads done
        } else {
            asm volatile("s_waitcnt vmcnt(0)" ::: "memory");
        }
        __builtin_amdgcn_s_barrier();                        // all waves' cur-buffer done
        const u16* Asb = &As[cur][0];
        const u16* Bsb = &Bs[cur][0];
#pragma unroll
        for (int kh = 0; kh < 2; ++kh) {
            short8 af[8], bf[4];
            int q = kh * 4 + (lane >> 4);
#pragma unroll
            for (int t = 0; t < 8; ++t) {
                int r = wm * 128 + t * 16 + (lane & 15);
                int pq = q ^ (r & 7);
                af[t] = *(const short8*)(Asb + r * 64 + pq * 8);
            }
#pragma unroll
            for (int t = 0; t < 4; ++t) {
                int rb = wn * 64 + t * 16 + (lane & 15);
                int pqb = q ^ (rb & 7);
                bf[t] = *(const short8*)(Bsb + rb * 64 + pqb * 8);
            }
#pragma unroll
            for (int mt = 0; mt < 8; ++mt)
#pragma unroll
                for (int nt = 0; nt < 4; ++nt)
                    acc[mt][nt] = __builtin_amdgcn_mfma_f32_16x16x32_bf16(af[mt], bf[nt], acc[mt][nt], 0, 0, 0);
        }
        __builtin_amdgcn_s_barrier();                        // reads of cur done before overwrite
        cur ^= 1;
    }
    float* P = part + (size_t)ks * NROI * NHID;
    int m_base = mb * 256 + wm * 128, n_base = nb * 256 + wn * 64;
#pragma unroll
    for (int mt = 0; mt < 8; ++mt)
#pragma unroll
        for (int nt = 0; nt < 4; ++nt)
#pragma unroll
            for (int i = 0; i < 4; ++i) {
                int m = m_base + mt * 16 + (lane >> 4) * 4 + i;
                int n = n_base + nt * 16 + (lane & 15);
                P[(size_t)m * NHID + n] = acc[mt][nt][i];
            }
}

// ---------------- fused: split-K reduce + bias + relu + GEMM2 + sigmoid + apply ----------------
// G2=4 rois per block: w2t row loads (200KB/roi before) are now shared across 4 rois,
// cutting w2t L2/L3 re-read traffic 205MB -> 51MB.
__global__ __launch_bounds__(256) void gemm2_apply(const float* __restrict__ part,
                                                   const float* __restrict__ b1,
                                                   const float* __restrict__ w2t,
                                                   const float* __restrict__ b2,
                                                   const u16* __restrict__ flat,
                                                   float* __restrict__ out) {
    __shared__ __align__(16) float hrow[G2][NHID];   // 16 KB
    __shared__ float partial[256];
    __shared__ float mrow[G2][49];
    int i0 = blockIdx.x * G2;
    int tid = threadIdx.x;
    // reduce split-K partials for G2 rois' hid rows + bias + relu, into LDS
    float4 bias = ((const float4*)b1)[tid];
#pragma unroll
    for (int g = 0; g < G2; ++g) {
        float4 s = bias;
        size_t base = (size_t)(i0 + g) * 256 + tid;   // float4 index within one K-slice
#pragma unroll
        for (int j = 0; j < KSPLIT; ++j) {
            float4 p = ((const float4*)part)[(size_t)j * 262144 + base];
            s.x += p.x; s.y += p.y; s.z += p.z; s.w += p.w;
        }
        float4 r;
        r.x = fmaxf(s.x, 0.f); r.y = fmaxf(s.y, 0.f);
        r.z = fmaxf(s.z, 0.f); r.w = fmaxf(s.w, 0.f);
        ((float4*)hrow[g])[tid] = r;
    }
    __syncthreads();
    float p[G2] = {};
    if (tid < 245) {
        int j = tid / 5, kc = tid - (tid / 5) * 5;
        int k0 = (256 * kc) / 5, k1 = (256 * (kc + 1)) / 5;   // float4 chunks
        const float4* wv = (const float4*)(w2t + (size_t)j * NHID);
        for (int k = k0; k < k1; ++k) {
            float4 b = wv[k];
#pragma unroll
            for (int g = 0; g < G2; ++g) {
                float4 a = ((const float4*)hrow[g])[k];
                p[g] += a.x * b.x + a.y * b.y + a.z * b.z + a.w * b.w;
            }
        }
    }
#pragma unroll
    for (int g = 0; g < G2; ++g) {
        partial[tid] = p[g];
        __syncthreads();
        if (tid < 49) {
            float s = b2[tid];
#pragma unroll
            for (int q = 0; q < 5; ++q) s += partial[tid * 5 + q];
            mrow[g][tid] = 1.f / (1.f + expf(-s));
        }
        __syncthreads();
    }
#pragma unroll 1
    for (int g = 0; g < G2; ++g) {
        const uint2* fl = (const uint2*)(flat + (size_t)(i0 + g) * KDIM);
        float4* op = (float4*)(out + (size_t)(i0 + g) * KDIM);
#pragma unroll 1
        for (int idx = tid; idx < 3136; idx += 256) {
            uint2 v = fl[idx];
            int e = idx * 4;
            int pp = e - (e / 49) * 49;
            float4 r;
            r.x = bf_lo(v.x) * mrow[g][pp]; if (++pp == 49) pp = 0;
            r.y = bf_hi(v.x) * mrow[g][pp]; if (++pp == 49) pp = 0;
            r.z = bf_lo(v.y) * mrow[g][pp]; if (++pp == 49) pp = 0;
            r.w = bf_hi(v.y) * mrow[g][pp];
            op[idx] = r;
        }
    }
}

extern "C" void kernel_launch(void* const* d_in, const int* in_sizes, int n_in,
                              void* d_out, int out_size, void* d_ws, size_t ws_size,
                              hipStream_t stream) {
    const float* features = (const float*)d_in[0];
    const float* rois     = (const float*)d_in[1];
    const float* w1       = (const float*)d_in[2];
    const float* b1       = (const float*)d_in[3];
    const float* w2       = (const float*)d_in[4];
    const float* b2       = (const float*)d_in[5];
    float* out = (float*)d_out;
    char* ws = (char*)d_ws;

    u16* featT  = (u16*)(ws);                      // 67,108,864
    u16* flat   = (u16*)(ws + 67108864);           // 25,690,112
    u16* w1t    = (u16*)(ws + 92798976);           // 25,690,112
    float* part = (float*)(ws + 118489088);        // 58,720,256 (KSPLIT=14)
    float* w2t  = (float*)(ws + 177209344);        // 200,704

    tfeat<<<2048, 256, 0, stream>>>(features, featT);
    roi_align<<<NROI, 256, 0, stream>>>(featT, rois, flat);
    tw1<<<784, 256, 0, stream>>>(w1, w1t);
    tw2<<<49, 256, 0, stream>>>(w2, w2t);
    gemm1<<<dim3(4, 4, KSPLIT), 512, 0, stream>>>(flat, w1t, part);
    gemm2_apply<<<NROI / G2, 256, 0, stream>>>(part, b1, w2t, b2, flat, out);
}